// Round 6
// baseline (864.721 us; speedup 1.0000x reference)
//
#include <hip/hip_runtime.h>
#include <hip/hip_bf16.h>
#include <cstdint>
#include <cstddef>

// B=2, S=2048, D=1024, R=64, H=16, DH=64, N=32; BS=4096
typedef unsigned short u16;
typedef short bfrag __attribute__((ext_vector_type(8)));     // 8 bf16 = 4 VGPRs
typedef float f32x4 __attribute__((ext_vector_type(4)));
typedef u16 u16x8 __attribute__((ext_vector_type(8)));

__device__ __forceinline__ u16 f2bf(float v) {
    union { float f; unsigned u; } a; a.f = v;
    unsigned r = a.u + 0x7fff + ((a.u >> 16) & 1);   // RNE
    return (u16)(r >> 16);
}
__device__ __forceinline__ float bf2f(u16 u) {
    union { unsigned u; float f; } a; a.u = ((unsigned)u) << 16;
    return a.f;
}
// cheap split: hi = truncate-to-bf16 (bit mask), lo = RNE(v - hi). |lo|<=2^-8|v|,
// residual after 3-MFMA ~2^-16 relative — fine for ~2^-13 score accuracy target.
__device__ __forceinline__ void split_trunc(float v, u16& hi, u16& lo) {
    union { float f; unsigned u; } a; a.f = v;
    unsigned hb = a.u & 0xFFFF0000u;
    hi = (u16)(hb >> 16);
    union { unsigned u; float f; } b; b.u = hb;
    lo = f2bf(v - b.f);
}
__device__ __forceinline__ f32x4 mfma_bf16(bfrag a, bfrag b, f32x4 c) {
    return __builtin_amdgcn_mfma_f32_16x16x32_bf16(a, b, c, 0, 0, 0);
}
__device__ __forceinline__ void async_copy16(const void* g, void* l) {
    __builtin_amdgcn_global_load_lds(
        (const __attribute__((address_space(1))) unsigned*)g,
        (__attribute__((address_space(3))) unsigned*)l, 16, 0, 0);
}

// ---------------------------------------------------------------------------
// elementwise cast fp32 -> bf16 hi (+lo if SPLIT); n4 = count/4
// ---------------------------------------------------------------------------
template<int SPLIT>
__global__ __launch_bounds__(256) void cast_split(const float* __restrict__ s,
                                                  u16* __restrict__ dh,
                                                  u16* __restrict__ dl, int n4)
{
    int i = blockIdx.x * 256 + threadIdx.x;
    if (i >= n4) return;
    float4 v = ((const float4*)s)[i];
    float vv[4] = {v.x, v.y, v.z, v.w};
    ushort4 h, l;
    u16* hp = (u16*)&h; u16* lp = (u16*)&l;
#pragma unroll
    for (int e = 0; e < 4; ++e) {
        u16 hb = f2bf(vv[e]);
        hp[e] = hb;
        if (SPLIT) lp[e] = f2bf(vv[e] - bf2f(hb));
    }
    ((ushort4*)dh)[i] = h;
    if (SPLIT) ((ushort4*)dl)[i] = l;
}

// ---------------------------------------------------------------------------
// transpose + cast: dst[z*C + c][r] = src[z*R*C + r*C + c]; dst pitch = dpitch
// ---------------------------------------------------------------------------
template<int SPLIT>
__global__ __launch_bounds__(256) void transpose_cast(const float* __restrict__ src,
                                                      u16* __restrict__ dh,
                                                      u16* __restrict__ dl,
                                                      int R, int C, int dpitch)
{
    __shared__ float t[32][33];
    int z = blockIdx.z;
    const float* s = src + (size_t)z * R * C;
    int r0 = blockIdx.y * 32, c0 = blockIdx.x * 32;
    int tx = threadIdx.x & 31, ty = threadIdx.x >> 5;
#pragma unroll
    for (int p = 0; p < 4; ++p)
        t[ty + p * 8][tx] = s[(size_t)(r0 + ty + p * 8) * C + c0 + tx];
    __syncthreads();
#pragma unroll
    for (int p = 0; p < 4; ++p) {
        int rr = ty + p * 8;
        float v = t[tx][rr];
        size_t di = (size_t)(z * C + c0 + rr) * dpitch + r0 + tx;
        u16 hb = f2bf(v);
        dh[di] = hb;
        if (SPLIT) dl[di] = f2bf(v - bf2f(hb));
    }
}

// ---------------------------------------------------------------------------
// MFMA GEMM 128x128 (outproj only): C = A @ BT^T, BK=32, bf16 single.
// ---------------------------------------------------------------------------
template<int SPLIT>
__global__ __launch_bounds__(256) void gemm_mfma(const u16* __restrict__ Agh,
                                                 const u16* __restrict__ Agl,
                                                 const u16* __restrict__ Bgh,
                                                 const u16* __restrict__ Bgl,
                                                 float* __restrict__ C,
                                                 int M, int N, int K)
{
    constexpr int NBUF = SPLIT ? 4 : 2;
    __shared__ u16 lds[NBUF * 4096];
    u16* Ath = lds;
    u16* Atl = SPLIT ? (lds + 4096) : lds;
    u16* Bth = lds + (SPLIT ? 8192 : 4096);
    u16* Btl = SPLIT ? (lds + 12288) : lds;

    const int tid  = threadIdx.x;
    const int lane = tid & 63;
    const int wv   = tid >> 6;
    const int q    = lane >> 4;
    const int tn   = lane & 15;
    const int wm   = (wv >> 1) * 64;
    const int wn   = (wv & 1) * 64;
    const int row0 = blockIdx.y * 128;
    const int col0 = blockIdx.x * 128;
    const int wbase = (tid & 192) * 8;

    f32x4 acc[4][4];
#pragma unroll
    for (int i = 0; i < 4; ++i)
#pragma unroll
        for (int j = 0; j < 4; ++j) acc[i][j] = 0.f;

    for (int k0 = 0; k0 < K; k0 += 32) {
#pragma unroll
        for (int shot = 0; shot < 2; ++shot) {
            int G = tid + shot * 256;
            int row = G >> 2, kgs = G & 3;
            int kgg = kgs ^ ((row >> 1) & 3);
            size_t goffB = (size_t)(col0 + row) * K + k0 + kgg * 8;
            async_copy16(Bgh + goffB, Bth + shot * 2048 + wbase);
            if (SPLIT) async_copy16(Bgl + goffB, Btl + shot * 2048 + wbase);
            size_t goffA = (size_t)(row0 + row) * K + k0 + kgg * 8;
            async_copy16(Agh + goffA, Ath + shot * 2048 + wbase);
            if (SPLIT) async_copy16(Agl + goffA, Atl + shot * 2048 + wbase);
        }
        __syncthreads();

        bfrag ah[4], bh[4], al[4], bl[4];
#pragma unroll
        for (int i = 0; i < 4; ++i) {
            int m = wm + i * 16 + tn;
            int g = m * 4 + (q ^ ((m >> 1) & 3));
            ah[i] = *(const bfrag*)(Ath + g * 8);
            if (SPLIT) al[i] = *(const bfrag*)(Atl + g * 8);
        }
#pragma unroll
        for (int j = 0; j < 4; ++j) {
            int n = wn + j * 16 + tn;
            int g = n * 4 + (q ^ ((n >> 1) & 3));
            bh[j] = *(const bfrag*)(Bth + g * 8);
            if (SPLIT) bl[j] = *(const bfrag*)(Btl + g * 8);
        }
#pragma unroll
        for (int i = 0; i < 4; ++i)
#pragma unroll
            for (int j = 0; j < 4; ++j) {
                acc[i][j] = mfma_bf16(ah[i], bh[j], acc[i][j]);
                if (SPLIT) {
                    acc[i][j] = mfma_bf16(ah[i], bl[j], acc[i][j]);
                    acc[i][j] = mfma_bf16(al[i], bh[j], acc[i][j]);
                }
            }
        __syncthreads();
    }

#pragma unroll
    for (int i = 0; i < 4; ++i)
#pragma unroll
        for (int j = 0; j < 4; ++j)
#pragma unroll
            for (int rg = 0; rg < 4; ++rg) {
                int row = row0 + wm + i * 16 + q * 4 + rg;
                int col = col0 + wn + j * 16 + tn;
                C[(size_t)row * N + col] = acc[i][j][rg];
            }
}

// ---------------------------------------------------------------------------
// Project GEMM, M-tile 256 x N-tile 128, BK=32, 4 waves (wave = 64 rows x 128).
// XCD swizzle: bid = (rt&7) + 8*((rt>>3)*nCol + ct) -> row-tiles pinned to XCD
// (A tiles L2-resident; B streams). A,B pre-cast bf16 via global_load_lds.
// ---------------------------------------------------------------------------
template<int SPLIT>
__global__ __launch_bounds__(256) void gemm256(const u16* __restrict__ Agh,
                                               const u16* __restrict__ Agl,
                                               const u16* __restrict__ Bgh,
                                               const u16* __restrict__ Bgl,
                                               float* __restrict__ C,
                                               int N, int K, int nCol)
{
    constexpr int LDSZ = SPLIT ? 24576 : 12288;
    __shared__ u16 lds[LDSZ];
    u16* Ath = lds;                               // 256x32
    u16* Atl = SPLIT ? (lds + 8192) : lds;
    u16* Bth = lds + (SPLIT ? 16384 : 8192);      // 128x32
    u16* Btl = SPLIT ? (lds + 20480) : lds;

    const int bid = blockIdx.x;
    const int low = bid & 7, idx = bid >> 3;
    const int rt = low + 8 * (idx / nCol);
    const int ct = idx % nCol;
    const int row0 = rt * 256, col0 = ct * 128;

    const int tid  = threadIdx.x;
    const int lane = tid & 63;
    const int wv   = tid >> 6;
    const int q    = lane >> 4;
    const int tn   = lane & 15;
    const int wbase = (tid & 192) * 8;

    f32x4 acc[4][8];
#pragma unroll
    for (int i = 0; i < 4; ++i)
#pragma unroll
        for (int j = 0; j < 8; ++j) acc[i][j] = 0.f;

    for (int k0 = 0; k0 < K; k0 += 32) {
        // A: 1024 granules = 4 shots
#pragma unroll
        for (int shot = 0; shot < 4; ++shot) {
            int G = tid + shot * 256;
            int row = G >> 2, s = G & 3;
            int gg = s ^ ((row >> 1) & 3);
            size_t goff = (size_t)(row0 + row) * K + k0 + gg * 8;
            async_copy16(Agh + goff, Ath + shot * 2048 + wbase);
            if (SPLIT) async_copy16(Agl + goff, Atl + shot * 2048 + wbase);
        }
        // B: 512 granules = 2 shots
#pragma unroll
        for (int shot = 0; shot < 2; ++shot) {
            int G = tid + shot * 256;
            int row = G >> 2, s = G & 3;
            int gg = s ^ ((row >> 1) & 3);
            size_t goff = (size_t)(col0 + row) * K + k0 + gg * 8;
            async_copy16(Bgh + goff, Bth + shot * 2048 + wbase);
            if (SPLIT) async_copy16(Bgl + goff, Btl + shot * 2048 + wbase);
        }
        __syncthreads();

        bfrag bh[8], bl[8];
#pragma unroll
        for (int j = 0; j < 8; ++j) {
            int n = j * 16 + tn;
            int g = n * 4 + (q ^ ((n >> 1) & 3));
            bh[j] = *(const bfrag*)(Bth + g * 8);
            if (SPLIT) bl[j] = *(const bfrag*)(Btl + g * 8);
        }
#pragma unroll
        for (int i = 0; i < 4; ++i) {
            int m = wv * 64 + i * 16 + tn;
            int g = m * 4 + (q ^ ((m >> 1) & 3));
            bfrag ah = *(const bfrag*)(Ath + g * 8);
            bfrag al;
            if (SPLIT) al = *(const bfrag*)(Atl + g * 8);
#pragma unroll
            for (int j = 0; j < 8; ++j) {
                acc[i][j] = mfma_bf16(ah, bh[j], acc[i][j]);
                if (SPLIT) {
                    acc[i][j] = mfma_bf16(ah, bl[j], acc[i][j]);
                    acc[i][j] = mfma_bf16(al, bh[j], acc[i][j]);
                }
            }
        }
        __syncthreads();
    }

#pragma unroll
    for (int i = 0; i < 4; ++i)
#pragma unroll
        for (int j = 0; j < 8; ++j)
#pragma unroll
            for (int rg = 0; rg < 4; ++rg) {
                int row = row0 + wv * 64 + i * 16 + q * 4 + rg;
                int col = col0 + j * 16 + tn;
                C[(size_t)row * N + col] = acc[i][j][rg];
            }
}

// ---------------------------------------------------------------------------
// Fused restore GEMMs, M-tile 256. Grid 384: bid=(ct)+8*(sel*16+rowt).
// XCD swizzle pins column-tiles: per-XCD L2 holds Rqk(hi+lo)+Rv col tiles
// (1.5 MB), shared across Q,K,V sels and all 16 row-tiles.
// Q,K: split (trunc-hi/RNE-lo A, 3 MFMA), epilogue bf16 hi/lo [bh][s][dh].
// V: single RNE bf16, epilogue transposed [bh][dh][s].
// ---------------------------------------------------------------------------
__global__ __launch_bounds__(256) void restore256(
    const float* __restrict__ h_q, const float* __restrict__ wQ,
    const float* __restrict__ h_k, const float* __restrict__ wK,
    const float* __restrict__ h_v, const float* __restrict__ wV,
    const u16* __restrict__ Rqh, const u16* __restrict__ Rql,
    const u16* __restrict__ Rvh,
    u16* __restrict__ Qh, u16* __restrict__ Ql,
    u16* __restrict__ Kh, u16* __restrict__ Kl,
    u16* __restrict__ Vt)
{
    __shared__ u16 lds[24576];
    u16* Ath = lds;                 // 256x32
    u16* Atl = lds + 8192;
    u16* Bth = lds + 16384;         // 128x32
    u16* Btl = lds + 20480;

    const int bid = blockIdx.x;
    const int ct  = bid & 7;
    const int idx = bid >> 3;
    const int sel = idx >> 4;                  // 0=Q,1=K,2=V
    const int rowt = idx & 15;
    const bool split = (sel < 2);
    const float* hA = (sel == 0) ? h_q : (sel == 1) ? h_k : h_v;
    const float* wA = (sel == 0) ? wQ  : (sel == 1) ? wK  : wV;
    const u16* Bgh = split ? Rqh : Rvh;
    const u16* Bgl = Rql;
    u16* Ch = (sel == 0) ? Qh : (sel == 1) ? Kh : Vt;
    u16* Cl = (sel == 0) ? Ql : Kl;
    const int K = 2048;
    const int row0 = rowt * 256, col0 = ct * 128;

    const int tid  = threadIdx.x;
    const int lane = tid & 63;
    const int wv   = tid >> 6;
    const int q    = lane >> 4;
    const int tn   = lane & 15;
    const int wbase = (tid & 192) * 8;

    f32x4 acc[4][8];
#pragma unroll
    for (int i = 0; i < 4; ++i)
#pragma unroll
        for (int j = 0; j < 8; ++j) acc[i][j] = 0.f;

    for (int k0 = 0; k0 < K; k0 += 32) {
        // B staging (async)
#pragma unroll
        for (int shot = 0; shot < 2; ++shot) {
            int G = tid + shot * 256;
            int row = G >> 2, s = G & 3;
            int gg = s ^ ((row >> 1) & 3);
            size_t goff = (size_t)(col0 + row) * K + k0 + gg * 8;
            async_copy16(Bgh + goff, Bth + shot * 2048 + wbase);
            if (split) async_copy16(Bgl + goff, Btl + shot * 2048 + wbase);
        }
        // A on the fly: one row per thread, 4 granules of 8
        {
            const int r = tid;
            const float wmul = wA[(size_t)(row0 + r) * 32 + (k0 >> 6)];
            const float* hp = hA + (size_t)(row0 + r) * 64 + (k0 & 63);
#pragma unroll
            for (int g4 = 0; g4 < 4; ++g4) {
                float4 v0 = *(const float4*)(hp + g4 * 8);
                float4 v1 = *(const float4*)(hp + g4 * 8 + 4);
                float vv[8] = {v0.x, v0.y, v0.z, v0.w, v1.x, v1.y, v1.z, v1.w};
                u16x8 hi, lo;
#pragma unroll
                for (int e = 0; e < 8; ++e) {
                    float val = vv[e] * wmul;
                    if (split) { u16 hb, lb; split_trunc(val, hb, lb); hi[e] = hb; lo[e] = lb; }
                    else hi[e] = f2bf(val);
                }
                int slot = g4 ^ ((r >> 1) & 3);
                *(u16x8*)(Ath + (r * 4 + slot) * 8) = hi;
                if (split) *(u16x8*)(Atl + (r * 4 + slot) * 8) = lo;
            }
        }
        __syncthreads();

        bfrag bh[8], bl[8];
#pragma unroll
        for (int j = 0; j < 8; ++j) {
            int n = j * 16 + tn;
            int g = n * 4 + (q ^ ((n >> 1) & 3));
            bh[j] = *(const bfrag*)(Bth + g * 8);
            if (split) bl[j] = *(const bfrag*)(Btl + g * 8);
        }
#pragma unroll
        for (int i = 0; i < 4; ++i) {
            int m = wv * 64 + i * 16 + tn;
            int g = m * 4 + (q ^ ((m >> 1) & 3));
            bfrag ah = *(const bfrag*)(Ath + g * 8);
            bfrag al;
            if (split) al = *(const bfrag*)(Atl + g * 8);
#pragma unroll
            for (int j = 0; j < 8; ++j) {
                acc[i][j] = mfma_bf16(ah, bh[j], acc[i][j]);
                if (split) {
                    acc[i][j] = mfma_bf16(ah, bl[j], acc[i][j]);
                    acc[i][j] = mfma_bf16(al, bh[j], acc[i][j]);
                }
            }
        }
        __syncthreads();
    }

#pragma unroll
    for (int i = 0; i < 4; ++i)
#pragma unroll
        for (int j = 0; j < 8; ++j)
#pragma unroll
            for (int rg = 0; rg < 4; ++rg) {
                int row = row0 + wv * 64 + i * 16 + q * 4 + rg;
                int col = col0 + j * 16 + tn;
                float v = acc[i][j][rg];
                if (split) {
                    size_t ix = (((size_t)(row >> 11) * 16 + (col >> 6)) << 17)
                              | ((size_t)(row & 2047) << 6) | (size_t)(col & 63);
                    u16 hb = f2bf(v);
                    Ch[ix] = hb;
                    Cl[ix] = f2bf(v - bf2f(hb));
                } else {
                    size_t ix = ((((size_t)(row >> 11) * 16 + (col >> 6)) * 64
                                 + (size_t)(col & 63)) << 11) | (size_t)(row & 2047);
                    Ch[ix] = f2bf(v);
                }
            }
}

// ---------------------------------------------------------------------------
// Mix: h1[bs,r] = sum_n w1[bs,n] * P[bs, n*64+r]  (optionally h2 with w2)
// ---------------------------------------------------------------------------
__global__ __launch_bounds__(256) void mix_kernel(const float* __restrict__ P,
                                                  const float* __restrict__ w1,
                                                  const float* __restrict__ w2,
                                                  float* __restrict__ h1,
                                                  float* __restrict__ h2,
                                                  int two)
{
    int tid = blockIdx.x * 256 + threadIdx.x;
    int bs = tid >> 6;
    int r  = tid & 63;
    const float* Pp = P + (size_t)bs * 2048 + r;
    float a = 0.f, b = 0.f;
#pragma unroll
    for (int n = 0; n < 32; ++n) {
        float p = Pp[n * 64];
        a = fmaf(w1[bs * 32 + n], p, a);
        if (two) b = fmaf(w2[bs * 32 + n], p, b);
    }
    h1[tid] = a;
    if (two) h2[tid] = b;
}

// ---------------------------------------------------------------------------
// K-split MFMA flash attention (flash-decoding style). See R5 notes.
// ---------------------------------------------------------------------------
template<int SHOTS>
__device__ __forceinline__ void stage_tile(u16* dst, const u16* src, int rowstride,
                                           int tid, int wuni)
{
#pragma unroll
    for (int shot = 0; shot < SHOTS; ++shot) {
        int sl = shot * 256 + tid;
        int m = sl >> 3, s = sl & 7, g = s ^ (m & 7);
        async_copy16(src + (size_t)m * rowstride + g * 8, dst + shot * 2048 + wuni);
    }
}

__global__ __launch_bounds__(256) void flash_part(const u16* __restrict__ Qh_g,
                                                  const u16* __restrict__ Ql_g,
                                                  const u16* __restrict__ Kh_g,
                                                  const u16* __restrict__ Kl_g,
                                                  const u16* __restrict__ Vt_g,
                                                  u16* __restrict__ Opart,
                                                  float* __restrict__ ml)
{
    const int bh = blockIdx.y;
    const int qb = blockIdx.x >> 3;
    const int c  = blockIdx.x & 7;
    const int g  = qb >> 2, rr = qb & 3;
    const int nch = g + 1;
    if (c >= nch) return;
    const int q0 = qb * 64;
    const int slot = bh * 144 + (qb + 2 * g * (g - 1) + rr * g) + c;

    const int tid = threadIdx.x;
    const int lane = tid & 63;
    const int wv = tid >> 6;
    const int q = lane >> 4;
    const int tn = lane & 15;
    const int wuni = (tid & 192) * 8;

    __shared__ u16 sQh[4096], sQl[4096], sKh[4096], sKl[4096], sVt[4096], sP[4096];

    const size_t qoff = ((size_t)bh * 2048 + q0) * 64;
    stage_tile<2>(sQh, Qh_g + qoff, 64, tid, wuni);
    stage_tile<2>(sQl, Ql_g + qoff, 64, tid, wuni);
    __syncthreads();

    bfrag qfh[2], qfl[2];
#pragma unroll
    for (int ks = 0; ks < 2; ++ks) {
        int m = wv * 16 + tn;
        int slt = (ks * 4 + q) ^ (m & 7);
        qfh[ks] = *(const bfrag*)(sQh + m * 64 + slt * 8);
        qfl[ks] = *(const bfrag*)(sQl + m * 64 + slt * 8);
    }

    float m_i[4], l_i[4];
    f32x4 acc_o[4];
#pragma unroll
    for (int ri = 0; ri < 4; ++ri) { m_i[ri] = -3.0e38f; l_i[ri] = 0.f; }
#pragma unroll
    for (int dt = 0; dt < 4; ++dt) acc_o[dt] = 0.f;

    const size_t kbase = (size_t)bh * 2048 * 64;
    const size_t vbase = (size_t)bh * 64 * 2048;
    const int kt_end = min(4 * c + 3, qb);

    for (int kt = 4 * c; kt <= kt_end; ++kt) {
        const int k0 = kt * 64;
        __syncthreads();
        stage_tile<2>(sKh, Kh_g + kbase + (size_t)k0 * 64, 64, tid, wuni);
        stage_tile<2>(sKl, Kl_g + kbase + (size_t)k0 * 64, 64, tid, wuni);
        stage_tile<2>(sVt, Vt_g + vbase + k0, 2048, tid, wuni);
        __syncthreads();

        f32x4 accs[4];
#pragma unroll
        for (int n = 0; n < 4; ++n) accs[n] = 0.f;
#pragma unroll
        for (int n = 0; n < 4; ++n) {
            int r = n * 16 + tn;
#pragma unroll
            for (int ks = 0; ks < 2; ++ks) {
                int slt = (ks * 4 + q) ^ (r & 7);
                bfrag kh = *(const bfrag*)(sKh + r * 64 + slt * 8);
                bfrag kl = *(const bfrag*)(sKl + r * 64 + slt * 8);
                accs[n] = mfma_bf16(qfh[ks], kh, accs[n]);
                accs[n] = mfma_bf16(qfh[ks], kl, accs[n]);
                accs[n] = mfma_bf16(qfl[ks], kh, accs[n]);
            }
        }
        const bool diag = (kt == qb);
#pragma unroll
        for (int n = 0; n < 4; ++n)
#pragma unroll
            for (int ri = 0; ri < 4; ++ri) {
                float v = accs[n][ri] * 0.125f;
                if (diag && (n * 16 + tn > wv * 16 + q * 4 + ri)) v = -3.0e38f;
                accs[n][ri] = v;
            }
        float alpha[4], mnew[4], ssum[4];
#pragma unroll
        for (int ri = 0; ri < 4; ++ri) {
            float mx = fmaxf(fmaxf(accs[0][ri], accs[1][ri]),
                             fmaxf(accs[2][ri], accs[3][ri]));
#pragma unroll
            for (int xm = 1; xm < 16; xm <<= 1)
                mx = fmaxf(mx, __shfl_xor(mx, xm, 64));
            mnew[ri] = fmaxf(m_i[ri], mx);
            alpha[ri] = __expf(m_i[ri] - mnew[ri]);
            m_i[ri] = mnew[ri];
            ssum[ri] = 0.f;
        }
#pragma unroll
        for (int n = 0; n < 4; ++n)
#pragma unroll
            for (int ri = 0; ri < 4; ++ri) {
                float p = __expf(accs[n][ri] - mnew[ri]);
                ssum[ri] += p;
                int m = wv * 16 + q * 4 + ri;
                int cc = n * 16 + tn;
                int slt = (cc >> 3) ^ (m & 7);
                sP[m * 64 + slt * 8 + (cc & 7)] = f2bf(p);
            }
#pragma unroll
        for (int ri = 0; ri < 4; ++ri) {
            float sm = ssum[ri];
#pragma unroll
            for (int xm = 1; xm < 16; xm <<= 1)
                sm += __shfl_xor(sm, xm, 64);
            l_i[ri] = l_i[ri] * alpha[ri] + sm;
#pragma unroll
            for (int dt = 0; dt < 4; ++dt) acc_o[dt][ri] *= alpha[ri];
        }
#pragma unroll
        for (int ks = 0; ks < 2; ++ks) {
            int m = wv * 16 + tn;
            int slt = (ks * 4 + q) ^ (m & 7);
            bfrag pf = *(const bfrag*)(sP + m * 64 + slt * 8);
#pragma unroll
            for (int dt = 0; dt < 4; ++dt) {
                int d = dt * 16 + tn;
                int vslt = (ks * 4 + q) ^ (d & 7);
                bfrag vf = *(const bfrag*)(sVt + d * 64 + vslt * 8);
                acc_o[dt] = mfma_bf16(pf, vf, acc_o[dt]);
            }
        }
    }

#pragma unroll
    for (int dt = 0; dt < 4; ++dt)
#pragma unroll
        for (int ri = 0; ri < 4; ++ri) {
            int row = wv * 16 + q * 4 + ri;
            Opart[(size_t)slot * 4096 + row * 64 + dt * 16 + tn] = f2bf(acc_o[dt][ri]);
        }
    if (tn == 0) {
#pragma unroll
        for (int ri = 0; ri < 4; ++ri) {
            int row = wv * 16 + q * 4 + ri;
            ml[(size_t)slot * 128 + row]      = m_i[ri];
            ml[(size_t)slot * 128 + 64 + row] = l_i[ri];
        }
    }
}

// ---------------------------------------------------------------------------
// Combine partials -> bf16 [bs][d]
// ---------------------------------------------------------------------------
__global__ __launch_bounds__(256) void flash_combine(const u16* __restrict__ Opart,
                                                     const float* __restrict__ ml,
                                                     u16* __restrict__ Am)
{
    const int qb = blockIdx.x, bh = blockIdx.y;
    const int g = qb >> 2, rr = qb & 3;
    const int nch = g + 1;
    const int base = bh * 144 + (qb + 2 * g * (g - 1) + rr * g);
    const int tid = threadIdx.x;
    const int row = tid >> 2;
    const int c0  = (tid & 3) * 16;

    float mstar = -3.0e38f;
    float mc[8];
#pragma unroll
    for (int c = 0; c < 8; ++c) {
        if (c < nch) {
            mc[c] = ml[(size_t)(base + c) * 128 + row];
            mstar = fmaxf(mstar, mc[c]);
        }
    }
    float lstar = 0.f, wc[8];
#pragma unroll
    for (int c = 0; c < 8; ++c) {
        if (c < nch) {
            wc[c] = __expf(mc[c] - mstar);
            lstar += ml[(size_t)(base + c) * 128 + 64 + row] * wc[c];
        }
    }
    float o[16];
#pragma unroll
    for (int j = 0; j < 16; ++j) o[j] = 0.f;
    for (int c = 0; c < nch; ++c) {
        const u16* p = Opart + (size_t)(base + c) * 4096 + row * 64 + c0;
        u16x8 v0 = *(const u16x8*)p;
        u16x8 v1 = *(const u16x8*)(p + 8);
#pragma unroll
        for (int j = 0; j < 8; ++j) {
            o[j]     = fmaf(bf2f(v0[j]), wc[c], o[j]);
            o[j + 8] = fmaf(bf2f(v1[j]), wc[c], o[j + 8]);
        }
    }
    float inv = 1.0f / lstar;
    int srow = qb * 64 + row;
    size_t obase = ((size_t)(bh >> 4) * 2048 + srow) * 1024
                 + (size_t)((bh & 15) * 64 + c0);
    u16x8 w0, w1;
#pragma unroll
    for (int j = 0; j < 8; ++j) {
        w0[j] = f2bf(o[j] * inv);
        w1[j] = f2bf(o[j + 8] * inv);
    }
    *(u16x8*)(Am + obase)     = w0;
    *(u16x8*)(Am + obase + 8) = w1;
}

// ---------------------------------------------------------------------------
extern "C" void kernel_launch(void* const* d_in, const int* in_sizes, int n_in,
                              void* d_out, int out_size, void* d_ws, size_t ws_size,
                              hipStream_t stream)
{
    const float* x     = (const float*)d_in[0];
    const float* wfqkQ = (const float*)d_in[1];
    const float* wfqkK = (const float*)d_in[2];
    const float* wfv   = (const float*)d_in[3];
    const float* wrqkQ = (const float*)d_in[4];
    const float* wrqkK = (const float*)d_in[5];
    const float* wrv   = (const float*)d_in[6];
    const float* f_qk  = (const float*)d_in[7];
    const float* f_v   = (const float*)d_in[8];
    const float* r_qk  = (const float*)d_in[9];
    const float* r_v   = (const float*)d_in[10];
    const float* W_O   = (const float*)d_in[11];
    float* out = (float*)d_out;

    const size_t MB = 1u << 20;
    char* w8 = (char*)d_ws;
    u16*  WOb   = (u16*)(w8 + 0);          //  2MB [1024][1024] (live to the end)
    u16*  FqkTh = (u16*)(w8 + 2  * MB);    //  4MB [2048][1024]
    u16*  FqkTl = (u16*)(w8 + 6  * MB);
    u16*  FvT   = (u16*)(w8 + 10 * MB);
    u16*  RqkTh = (u16*)(w8 + 14 * MB);    //  4MB [1024][2048]
    u16*  RqkTl = (u16*)(w8 + 18 * MB);
    u16*  RvT   = (u16*)(w8 + 22 * MB);
    float* h_q  = (float*)(w8 + 26 * MB);  //  1MB each
    float* h_k  = (float*)(w8 + 27 * MB);
    float* h_v  = (float*)(w8 + 28 * MB);
    u16*  x_hi  = (u16*)(w8 + 30 * MB);    //  8MB
    u16*  x_lo  = (u16*)(w8 + 38 * MB);
    float* P    = (float*)(w8 + 48 * MB);  // 32MB fp32 (dead after mix)
    u16*  Qh    = (u16*)(w8 + 48 * MB);    //  8MB each, [bh][s][dh] (over P)
    u16*  Ql    = (u16*)(w8 + 56 * MB);
    u16*  Kh    = (u16*)(w8 + 64 * MB);
    u16*  Kl    = (u16*)(w8 + 72 * MB);
    u16*  Vt    = (u16*)(w8 + 80 * MB);    //  8MB [bh][dh][s]
    u16*  Am    = (u16*)(w8 + 88 * MB);    //  8MB bf16 attn out
    u16*  Opart = (u16*)(w8 + 2  * MB);    // 37.75MB (over F/R region, dead then? no
                                           //  -- over FqkT* which is dead after project)
    float* mlws = (float*)(w8 + 40 * MB);  // 2.36MB

    dim3 blk(256);

    // casts / transposes
    cast_split<1><<<dim3(4096), blk, 0, stream>>>(x, x_hi, x_lo, 1024 * 1024);
    cast_split<0><<<dim3(1024), blk, 0, stream>>>(W_O, WOb, nullptr, 256 * 1024);
    transpose_cast<1><<<dim3(2, 32, 32), blk, 0, stream>>>(f_qk, FqkTh, FqkTl, 1024, 64, 1024);
    transpose_cast<0><<<dim3(2, 32, 32), blk, 0, stream>>>(f_v,  FvT,   nullptr, 1024, 64, 1024);
    transpose_cast<1><<<dim3(32, 64, 1), blk, 0, stream>>>(r_qk, RqkTh, RqkTl, 2048, 1024, 2048);
    transpose_cast<0><<<dim3(32, 64, 1), blk, 0, stream>>>(r_v,  RvT,   nullptr, 2048, 1024, 2048);

    // project (M=256 tiles, row-resident XCD swizzle) + mix
    gemm256<1><<<dim3(256), blk, 0, stream>>>(x_hi, x_lo, FqkTh, FqkTl, P, 2048, 1024, 16);
    mix_kernel<<<dim3(1024), blk, 0, stream>>>(P, wfqkQ, wfqkK, h_q, h_k, 1);
    gemm256<0><<<dim3(256), blk, 0, stream>>>(x_hi, nullptr, FvT, nullptr, P, 2048, 1024, 16);
    mix_kernel<<<dim3(1024), blk, 0, stream>>>(P, wfv, nullptr, h_v, nullptr, 0);

    // fused restore (M=256, column-resident XCD swizzle) -> bf16 attn operands
    restore256<<<dim3(384), blk, 0, stream>>>(h_q, wrqkQ, h_k, wrqkK, h_v, wrv,
                                              RqkTh, RqkTl, RvT,
                                              Qh, Ql, Kh, Kl, Vt);

    // K-split flash attention: partials + combine
    flash_part<<<dim3(256, 32), blk, 0, stream>>>(Qh, Ql, Kh, Kl, Vt, Opart, mlws);
    flash_combine<<<dim3(32, 32), blk, 0, stream>>>(Opart, mlws, Am);

    // output projection
    gemm_mfma<0><<<dim3(8, 32), blk, 0, stream>>>(Am, nullptr, WOb, nullptr, out,
                                                  4096, 1024, 1024);
}

// Round 7
// 613.732 us; speedup vs baseline: 1.4090x; 1.4090x over previous
//
#include <hip/hip_runtime.h>
#include <hip/hip_bf16.h>
#include <cstdint>
#include <cstddef>

// B=2, S=2048, D=1024, R=64, H=16, DH=64, N=32; BS=4096
typedef unsigned short u16;
typedef short bfrag __attribute__((ext_vector_type(8)));     // 8 bf16 = 4 VGPRs
typedef float f32x4 __attribute__((ext_vector_type(4)));
typedef u16 u16x8 __attribute__((ext_vector_type(8)));

__device__ __forceinline__ u16 f2bf(float v) {
    union { float f; unsigned u; } a; a.f = v;
    unsigned r = a.u + 0x7fff + ((a.u >> 16) & 1);   // RNE
    return (u16)(r >> 16);
}
__device__ __forceinline__ float bf2f(u16 u) {
    union { unsigned u; float f; } a; a.u = ((unsigned)u) << 16;
    return a.f;
}
// cheap split: hi = truncate-to-bf16 (bit mask), lo = RNE(v - hi).
__device__ __forceinline__ void split_trunc(float v, u16& hi, u16& lo) {
    union { float f; unsigned u; } a; a.f = v;
    unsigned hb = a.u & 0xFFFF0000u;
    hi = (u16)(hb >> 16);
    union { unsigned u; float f; } b; b.u = hb;
    lo = f2bf(v - b.f);
}
__device__ __forceinline__ f32x4 mfma_bf16(bfrag a, bfrag b, f32x4 c) {
    return __builtin_amdgcn_mfma_f32_16x16x32_bf16(a, b, c, 0, 0, 0);
}
__device__ __forceinline__ void async_copy16(const void* g, void* l) {
    __builtin_amdgcn_global_load_lds(
        (const __attribute__((address_space(1))) unsigned*)g,
        (__attribute__((address_space(3))) unsigned*)l, 16, 0, 0);
}

// ---------------------------------------------------------------------------
// elementwise cast fp32 -> bf16 hi (+lo if SPLIT); n4 = count/4
// ---------------------------------------------------------------------------
template<int SPLIT>
__global__ __launch_bounds__(256) void cast_split(const float* __restrict__ s,
                                                  u16* __restrict__ dh,
                                                  u16* __restrict__ dl, int n4)
{
    int i = blockIdx.x * 256 + threadIdx.x;
    if (i >= n4) return;
    float4 v = ((const float4*)s)[i];
    float vv[4] = {v.x, v.y, v.z, v.w};
    ushort4 h, l;
    u16* hp = (u16*)&h; u16* lp = (u16*)&l;
#pragma unroll
    for (int e = 0; e < 4; ++e) {
        u16 hb = f2bf(vv[e]);
        hp[e] = hb;
        if (SPLIT) lp[e] = f2bf(vv[e] - bf2f(hb));
    }
    ((ushort4*)dh)[i] = h;
    if (SPLIT) ((ushort4*)dl)[i] = l;
}

// ---------------------------------------------------------------------------
// transpose + cast: dst[z*C + c][r] = src[z*R*C + r*C + c]; dst pitch = dpitch
// ---------------------------------------------------------------------------
template<int SPLIT>
__global__ __launch_bounds__(256) void transpose_cast(const float* __restrict__ src,
                                                      u16* __restrict__ dh,
                                                      u16* __restrict__ dl,
                                                      int R, int C, int dpitch)
{
    __shared__ float t[32][33];
    int z = blockIdx.z;
    const float* s = src + (size_t)z * R * C;
    int r0 = blockIdx.y * 32, c0 = blockIdx.x * 32;
    int tx = threadIdx.x & 31, ty = threadIdx.x >> 5;
#pragma unroll
    for (int p = 0; p < 4; ++p)
        t[ty + p * 8][tx] = s[(size_t)(r0 + ty + p * 8) * C + c0 + tx];
    __syncthreads();
#pragma unroll
    for (int p = 0; p < 4; ++p) {
        int rr = ty + p * 8;
        float v = t[tx][rr];
        size_t di = (size_t)(z * C + c0 + rr) * dpitch + r0 + tx;
        u16 hb = f2bf(v);
        dh[di] = hb;
        if (SPLIT) dl[di] = f2bf(v - bf2f(hb));
    }
}

// ---------------------------------------------------------------------------
// MFMA GEMM 128x128, BK=32, 4 waves, 1-D grid with XCD swizzle:
//   ct = (bid&7) + 8*(idx % CTH), rowt = idx / CTH   (idx = bid>>3)
// -> column tiles pinned per XCD (B operand L2-resident).
// SPLIT: 3-MFMA hi/lo (~fp32). A,B pre-cast bf16 via global_load_lds.
// ---------------------------------------------------------------------------
template<int SPLIT, int CTH>
__global__ __launch_bounds__(256) void gemm_mfma(const u16* __restrict__ Agh,
                                                 const u16* __restrict__ Agl,
                                                 const u16* __restrict__ Bgh,
                                                 const u16* __restrict__ Bgl,
                                                 float* __restrict__ C,
                                                 int M, int N, int K)
{
    constexpr int NBUF = SPLIT ? 4 : 2;
    __shared__ u16 lds[NBUF * 4096];
    u16* Ath = lds;
    u16* Atl = SPLIT ? (lds + 4096) : lds;
    u16* Bth = lds + (SPLIT ? 8192 : 4096);
    u16* Btl = SPLIT ? (lds + 12288) : lds;

    const int bid = blockIdx.x;
    const int idx = bid >> 3;
    const int ct  = (bid & 7) + 8 * (idx % CTH);
    const int rowt = idx / CTH;
    const int row0 = rowt * 128;
    const int col0 = ct * 128;

    const int tid  = threadIdx.x;
    const int lane = tid & 63;
    const int wv   = tid >> 6;
    const int q    = lane >> 4;
    const int tn   = lane & 15;
    const int wm   = (wv >> 1) * 64;
    const int wn   = (wv & 1) * 64;
    const int wbase = (tid & 192) * 8;

    f32x4 acc[4][4];
#pragma unroll
    for (int i = 0; i < 4; ++i)
#pragma unroll
        for (int j = 0; j < 4; ++j) acc[i][j] = 0.f;

    for (int k0 = 0; k0 < K; k0 += 32) {
#pragma unroll
        for (int shot = 0; shot < 2; ++shot) {
            int G = tid + shot * 256;
            int row = G >> 2, kgs = G & 3;
            int kgg = kgs ^ ((row >> 1) & 3);
            size_t goffB = (size_t)(col0 + row) * K + k0 + kgg * 8;
            async_copy16(Bgh + goffB, Bth + shot * 2048 + wbase);
            if (SPLIT) async_copy16(Bgl + goffB, Btl + shot * 2048 + wbase);
            size_t goffA = (size_t)(row0 + row) * K + k0 + kgg * 8;
            async_copy16(Agh + goffA, Ath + shot * 2048 + wbase);
            if (SPLIT) async_copy16(Agl + goffA, Atl + shot * 2048 + wbase);
        }
        __syncthreads();

        bfrag ah[4], bh[4], al[4], bl[4];
#pragma unroll
        for (int i = 0; i < 4; ++i) {
            int m = wm + i * 16 + tn;
            int g = m * 4 + (q ^ ((m >> 1) & 3));
            ah[i] = *(const bfrag*)(Ath + g * 8);
            if (SPLIT) al[i] = *(const bfrag*)(Atl + g * 8);
        }
#pragma unroll
        for (int j = 0; j < 4; ++j) {
            int n = wn + j * 16 + tn;
            int g = n * 4 + (q ^ ((n >> 1) & 3));
            bh[j] = *(const bfrag*)(Bth + g * 8);
            if (SPLIT) bl[j] = *(const bfrag*)(Btl + g * 8);
        }
#pragma unroll
        for (int i = 0; i < 4; ++i)
#pragma unroll
            for (int j = 0; j < 4; ++j) {
                acc[i][j] = mfma_bf16(ah[i], bh[j], acc[i][j]);
                if (SPLIT) {
                    acc[i][j] = mfma_bf16(ah[i], bl[j], acc[i][j]);
                    acc[i][j] = mfma_bf16(al[i], bh[j], acc[i][j]);
                }
            }
        __syncthreads();
    }

#pragma unroll
    for (int i = 0; i < 4; ++i)
#pragma unroll
        for (int j = 0; j < 4; ++j)
#pragma unroll
            for (int rg = 0; rg < 4; ++rg) {
                int row = row0 + wm + i * 16 + q * 4 + rg;
                int col = col0 + wn + j * 16 + tn;
                C[(size_t)row * N + col] = acc[i][j][rg];
            }
}

// ---------------------------------------------------------------------------
// Fused restore GEMMs, 128x128 tiles, grid 768 (1-D):
//   ct = bid&7 (pinned per XCD: Rqk hi+lo + Rv col tiles = 1.5 MB L2-resident),
//   idx = bid>>3, sel = idx>>5 (0=Q,1=K,2=V), rowt = idx&31.
// Q,K: split (trunc-hi/RNE-lo A, 3 MFMA), epilogue bf16 hi/lo [bh][s][dh].
// V: single RNE bf16, epilogue transposed [bh][dh][s].
// ---------------------------------------------------------------------------
__global__ __launch_bounds__(256) void restore_mega(
    const float* __restrict__ h_q, const float* __restrict__ wQ,
    const float* __restrict__ h_k, const float* __restrict__ wK,
    const float* __restrict__ h_v, const float* __restrict__ wV,
    const u16* __restrict__ Rqh, const u16* __restrict__ Rql,
    const u16* __restrict__ Rvh,
    u16* __restrict__ Qh, u16* __restrict__ Ql,
    u16* __restrict__ Kh, u16* __restrict__ Kl,
    u16* __restrict__ Vt)
{
    const int bid = blockIdx.x;
    const int ct  = bid & 7;
    const int idx = bid >> 3;
    const int sel = idx >> 5;                  // 0=Q,1=K,2=V
    const int rowt = idx & 31;
    const bool split = (sel < 2);
    const float* hA = (sel == 0) ? h_q : (sel == 1) ? h_k : h_v;
    const float* wA = (sel == 0) ? wQ  : (sel == 1) ? wK  : wV;
    const u16* Bgh = split ? Rqh : Rvh;
    const u16* Bgl = Rql;
    u16* Ch = (sel == 0) ? Qh : (sel == 1) ? Kh : Vt;
    u16* Cl = (sel == 0) ? Ql : Kl;
    const int K = 2048;
    const int row0 = rowt * 128, col0 = ct * 128;

    __shared__ u16 lds[16384];
    u16* Ath = lds;
    u16* Atl = lds + 4096;
    u16* Bth = lds + 8192;
    u16* Btl = lds + 12288;

    const int tid  = threadIdx.x;
    const int lane = tid & 63;
    const int wv   = tid >> 6;
    const int q    = lane >> 4;
    const int tn   = lane & 15;
    const int wm   = (wv >> 1) * 64;
    const int wn   = (wv & 1) * 64;
    const int wbase = (tid & 192) * 8;

    f32x4 acc[4][4];
#pragma unroll
    for (int i = 0; i < 4; ++i)
#pragma unroll
        for (int j = 0; j < 4; ++j) acc[i][j] = 0.f;

    for (int k0 = 0; k0 < K; k0 += 32) {
        // B staging (async)
#pragma unroll
        for (int shot = 0; shot < 2; ++shot) {
            int G = tid + shot * 256;
            int row = G >> 2, kgs = G & 3;
            int kgg = kgs ^ ((row >> 1) & 3);
            size_t goff = (size_t)(col0 + row) * K + k0 + kgg * 8;
            async_copy16(Bgh + goff, Bth + shot * 2048 + wbase);
            if (split) async_copy16(Bgl + goff, Btl + shot * 2048 + wbase);
        }
        // A on the fly: hw product, trunc-split into hi/lo
        {
            const int r = tid >> 1;
            float wmul = wA[(size_t)(row0 + r) * 32 + (k0 >> 6)];
#pragma unroll
            for (int gi = 0; gi < 2; ++gi) {
                int gg = (tid & 1) * 2 + gi;
                const float* sp = hA + (size_t)(row0 + r) * 64 + (k0 & 63) + gg * 8;
                float4 v0 = *(const float4*)sp;
                float4 v1 = *(const float4*)(sp + 4);
                float vv[8] = {v0.x, v0.y, v0.z, v0.w, v1.x, v1.y, v1.z, v1.w};
                u16x8 hi, lo;
#pragma unroll
                for (int e = 0; e < 8; ++e) {
                    float val = vv[e] * wmul;
                    if (split) { u16 hb, lb; split_trunc(val, hb, lb); hi[e] = hb; lo[e] = lb; }
                    else hi[e] = f2bf(val);
                }
                int slot = r * 4 + (gg ^ ((r >> 1) & 3));
                *(u16x8*)(Ath + slot * 8) = hi;
                if (split) *(u16x8*)(Atl + slot * 8) = lo;
            }
        }
        __syncthreads();

        bfrag ah[4], bh[4], al[4], bl[4];
#pragma unroll
        for (int i = 0; i < 4; ++i) {
            int m = wm + i * 16 + tn;
            int g = m * 4 + (q ^ ((m >> 1) & 3));
            ah[i] = *(const bfrag*)(Ath + g * 8);
            if (split) al[i] = *(const bfrag*)(Atl + g * 8);
        }
#pragma unroll
        for (int j = 0; j < 4; ++j) {
            int n = wn + j * 16 + tn;
            int g = n * 4 + (q ^ ((n >> 1) & 3));
            bh[j] = *(const bfrag*)(Bth + g * 8);
            if (split) bl[j] = *(const bfrag*)(Btl + g * 8);
        }
#pragma unroll
        for (int i = 0; i < 4; ++i)
#pragma unroll
            for (int j = 0; j < 4; ++j) {
                acc[i][j] = mfma_bf16(ah[i], bh[j], acc[i][j]);
                if (split) {
                    acc[i][j] = mfma_bf16(ah[i], bl[j], acc[i][j]);
                    acc[i][j] = mfma_bf16(al[i], bh[j], acc[i][j]);
                }
            }
        __syncthreads();
    }

#pragma unroll
    for (int i = 0; i < 4; ++i)
#pragma unroll
        for (int j = 0; j < 4; ++j)
#pragma unroll
            for (int rg = 0; rg < 4; ++rg) {
                int row = row0 + wm + i * 16 + q * 4 + rg;
                int col = col0 + wn + j * 16 + tn;
                float v = acc[i][j][rg];
                if (split) {
                    size_t ix = (((size_t)(row >> 11) * 16 + (col >> 6)) << 17)
                              | ((size_t)(row & 2047) << 6) | (size_t)(col & 63);
                    u16 hb = f2bf(v);
                    Ch[ix] = hb;
                    Cl[ix] = f2bf(v - bf2f(hb));
                } else {
                    size_t ix = ((((size_t)(row >> 11) * 16 + (col >> 6)) * 64
                                 + (size_t)(col & 63)) << 11) | (size_t)(row & 2047);
                    Ch[ix] = f2bf(v);
                }
            }
}

// ---------------------------------------------------------------------------
// Mix: h1[bs,r] = sum_n w1[bs,n] * P[bs, n*64+r]  (optionally h2 with w2)
// ---------------------------------------------------------------------------
__global__ __launch_bounds__(256) void mix_kernel(const float* __restrict__ P,
                                                  const float* __restrict__ w1,
                                                  const float* __restrict__ w2,
                                                  float* __restrict__ h1,
                                                  float* __restrict__ h2,
                                                  int two)
{
    int tid = blockIdx.x * 256 + threadIdx.x;
    int bs = tid >> 6;
    int r  = tid & 63;
    const float* Pp = P + (size_t)bs * 2048 + r;
    float a = 0.f, b = 0.f;
#pragma unroll
    for (int n = 0; n < 32; ++n) {
        float p = Pp[n * 64];
        a = fmaf(w1[bs * 32 + n], p, a);
        if (two) b = fmaf(w2[bs * 32 + n], p, b);
    }
    h1[tid] = a;
    if (two) h2[tid] = b;
}

// ---------------------------------------------------------------------------
// K-split MFMA flash attention (flash-decoding style). See R5 notes.
// ---------------------------------------------------------------------------
template<int SHOTS>
__device__ __forceinline__ void stage_tile(u16* dst, const u16* src, int rowstride,
                                           int tid, int wuni)
{
#pragma unroll
    for (int shot = 0; shot < SHOTS; ++shot) {
        int sl = shot * 256 + tid;
        int m = sl >> 3, s = sl & 7, g = s ^ (m & 7);
        async_copy16(src + (size_t)m * rowstride + g * 8, dst + shot * 2048 + wuni);
    }
}

__global__ __launch_bounds__(256) void flash_part(const u16* __restrict__ Qh_g,
                                                  const u16* __restrict__ Ql_g,
                                                  const u16* __restrict__ Kh_g,
                                                  const u16* __restrict__ Kl_g,
                                                  const u16* __restrict__ Vt_g,
                                                  u16* __restrict__ Opart,
                                                  float* __restrict__ ml)
{
    const int bh = blockIdx.y;
    const int qb = blockIdx.x >> 3;
    const int c  = blockIdx.x & 7;
    const int g  = qb >> 2, rr = qb & 3;
    const int nch = g + 1;
    if (c >= nch) return;
    const int q0 = qb * 64;
    const int slot = bh * 144 + (qb + 2 * g * (g - 1) + rr * g) + c;

    const int tid = threadIdx.x;
    const int lane = tid & 63;
    const int wv = tid >> 6;
    const int q = lane >> 4;
    const int tn = lane & 15;
    const int wuni = (tid & 192) * 8;

    __shared__ u16 sQh[4096], sQl[4096], sKh[4096], sKl[4096], sVt[4096], sP[4096];

    const size_t qoff = ((size_t)bh * 2048 + q0) * 64;
    stage_tile<2>(sQh, Qh_g + qoff, 64, tid, wuni);
    stage_tile<2>(sQl, Ql_g + qoff, 64, tid, wuni);
    __syncthreads();

    bfrag qfh[2], qfl[2];
#pragma unroll
    for (int ks = 0; ks < 2; ++ks) {
        int m = wv * 16 + tn;
        int slt = (ks * 4 + q) ^ (m & 7);
        qfh[ks] = *(const bfrag*)(sQh + m * 64 + slt * 8);
        qfl[ks] = *(const bfrag*)(sQl + m * 64 + slt * 8);
    }

    float m_i[4], l_i[4];
    f32x4 acc_o[4];
#pragma unroll
    for (int ri = 0; ri < 4; ++ri) { m_i[ri] = -3.0e38f; l_i[ri] = 0.f; }
#pragma unroll
    for (int dt = 0; dt < 4; ++dt) acc_o[dt] = 0.f;

    const size_t kbase = (size_t)bh * 2048 * 64;
    const size_t vbase = (size_t)bh * 64 * 2048;
    const int kt_end = min(4 * c + 3, qb);

    for (int kt = 4 * c; kt <= kt_end; ++kt) {
        const int k0 = kt * 64;
        __syncthreads();
        stage_tile<2>(sKh, Kh_g + kbase + (size_t)k0 * 64, 64, tid, wuni);
        stage_tile<2>(sKl, Kl_g + kbase + (size_t)k0 * 64, 64, tid, wuni);
        stage_tile<2>(sVt, Vt_g + vbase + k0, 2048, tid, wuni);
        __syncthreads();

        f32x4 accs[4];
#pragma unroll
        for (int n = 0; n < 4; ++n) accs[n] = 0.f;
#pragma unroll
        for (int n = 0; n < 4; ++n) {
            int r = n * 16 + tn;
#pragma unroll
            for (int ks = 0; ks < 2; ++ks) {
                int slt = (ks * 4 + q) ^ (r & 7);
                bfrag kh = *(const bfrag*)(sKh + r * 64 + slt * 8);
                bfrag kl = *(const bfrag*)(sKl + r * 64 + slt * 8);
                accs[n] = mfma_bf16(qfh[ks], kh, accs[n]);
                accs[n] = mfma_bf16(qfh[ks], kl, accs[n]);
                accs[n] = mfma_bf16(qfl[ks], kh, accs[n]);
            }
        }
        const bool diag = (kt == qb);
#pragma unroll
        for (int n = 0; n < 4; ++n)
#pragma unroll
            for (int ri = 0; ri < 4; ++ri) {
                float v = accs[n][ri] * 0.125f;
                if (diag && (n * 16 + tn > wv * 16 + q * 4 + ri)) v = -3.0e38f;
                accs[n][ri] = v;
            }
        float alpha[4], mnew[4], ssum[4];
#pragma unroll
        for (int ri = 0; ri < 4; ++ri) {
            float mx = fmaxf(fmaxf(accs[0][ri], accs[1][ri]),
                             fmaxf(accs[2][ri], accs[3][ri]));
#pragma unroll
            for (int xm = 1; xm < 16; xm <<= 1)
                mx = fmaxf(mx, __shfl_xor(mx, xm, 64));
            mnew[ri] = fmaxf(m_i[ri], mx);
            alpha[ri] = __expf(m_i[ri] - mnew[ri]);
            m_i[ri] = mnew[ri];
            ssum[ri] = 0.f;
        }
#pragma unroll
        for (int n = 0; n < 4; ++n)
#pragma unroll
            for (int ri = 0; ri < 4; ++ri) {
                float p = __expf(accs[n][ri] - mnew[ri]);
                ssum[ri] += p;
                int m = wv * 16 + q * 4 + ri;
                int cc = n * 16 + tn;
                int slt = (cc >> 3) ^ (m & 7);
                sP[m * 64 + slt * 8 + (cc & 7)] = f2bf(p);
            }
#pragma unroll
        for (int ri = 0; ri < 4; ++ri) {
            float sm = ssum[ri];
#pragma unroll
            for (int xm = 1; xm < 16; xm <<= 1)
                sm += __shfl_xor(sm, xm, 64);
            l_i[ri] = l_i[ri] * alpha[ri] + sm;
#pragma unroll
            for (int dt = 0; dt < 4; ++dt) acc_o[dt][ri] *= alpha[ri];
        }
#pragma unroll
        for (int ks = 0; ks < 2; ++ks) {
            int m = wv * 16 + tn;
            int slt = (ks * 4 + q) ^ (m & 7);
            bfrag pf = *(const bfrag*)(sP + m * 64 + slt * 8);
#pragma unroll
            for (int dt = 0; dt < 4; ++dt) {
                int d = dt * 16 + tn;
                int vslt = (ks * 4 + q) ^ (d & 7);
                bfrag vf = *(const bfrag*)(sVt + d * 64 + vslt * 8);
                acc_o[dt] = mfma_bf16(pf, vf, acc_o[dt]);
            }
        }
    }

#pragma unroll
    for (int dt = 0; dt < 4; ++dt)
#pragma unroll
        for (int ri = 0; ri < 4; ++ri) {
            int row = wv * 16 + q * 4 + ri;
            Opart[(size_t)slot * 4096 + row * 64 + dt * 16 + tn] = f2bf(acc_o[dt][ri]);
        }
    if (tn == 0) {
#pragma unroll
        for (int ri = 0; ri < 4; ++ri) {
            int row = wv * 16 + q * 4 + ri;
            ml[(size_t)slot * 128 + row]      = m_i[ri];
            ml[(size_t)slot * 128 + 64 + row] = l_i[ri];
        }
    }
}

// ---------------------------------------------------------------------------
// Combine partials -> bf16 [bs][d]
// ---------------------------------------------------------------------------
__global__ __launch_bounds__(256) void flash_combine(const u16* __restrict__ Opart,
                                                     const float* __restrict__ ml,
                                                     u16* __restrict__ Am)
{
    const int qb = blockIdx.x, bh = blockIdx.y;
    const int g = qb >> 2, rr = qb & 3;
    const int nch = g + 1;
    const int base = bh * 144 + (qb + 2 * g * (g - 1) + rr * g);
    const int tid = threadIdx.x;
    const int row = tid >> 2;
    const int c0  = (tid & 3) * 16;

    float mstar = -3.0e38f;
    float mc[8];
#pragma unroll
    for (int c = 0; c < 8; ++c) {
        if (c < nch) {
            mc[c] = ml[(size_t)(base + c) * 128 + row];
            mstar = fmaxf(mstar, mc[c]);
        }
    }
    float lstar = 0.f, wc[8];
#pragma unroll
    for (int c = 0; c < 8; ++c) {
        if (c < nch) {
            wc[c] = __expf(mc[c] - mstar);
            lstar += ml[(size_t)(base + c) * 128 + 64 + row] * wc[c];
        }
    }
    float o[16];
#pragma unroll
    for (int j = 0; j < 16; ++j) o[j] = 0.f;
    for (int c = 0; c < nch; ++c) {
        const u16* p = Opart + (size_t)(base + c) * 4096 + row * 64 + c0;
        u16x8 v0 = *(const u16x8*)p;
        u16x8 v1 = *(const u16x8*)(p + 8);
#pragma unroll
        for (int j = 0; j < 8; ++j) {
            o[j]     = fmaf(bf2f(v0[j]), wc[c], o[j]);
            o[j + 8] = fmaf(bf2f(v1[j]), wc[c], o[j + 8]);
        }
    }
    float inv = 1.0f / lstar;
    int srow = qb * 64 + row;
    size_t obase = ((size_t)(bh >> 4) * 2048 + srow) * 1024
                 + (size_t)((bh & 15) * 64 + c0);
    u16x8 w0, w1;
#pragma unroll
    for (int j = 0; j < 8; ++j) {
        w0[j] = f2bf(o[j] * inv);
        w1[j] = f2bf(o[j + 8] * inv);
    }
    *(u16x8*)(Am + obase)     = w0;
    *(u16x8*)(Am + obase + 8) = w1;
}

// ---------------------------------------------------------------------------
extern "C" void kernel_launch(void* const* d_in, const int* in_sizes, int n_in,
                              void* d_out, int out_size, void* d_ws, size_t ws_size,
                              hipStream_t stream)
{
    const float* x     = (const float*)d_in[0];
    const float* wfqkQ = (const float*)d_in[1];
    const float* wfqkK = (const float*)d_in[2];
    const float* wfv   = (const float*)d_in[3];
    const float* wrqkQ = (const float*)d_in[4];
    const float* wrqkK = (const float*)d_in[5];
    const float* wrv   = (const float*)d_in[6];
    const float* f_qk  = (const float*)d_in[7];
    const float* f_v   = (const float*)d_in[8];
    const float* r_qk  = (const float*)d_in[9];
    const float* r_v   = (const float*)d_in[10];
    const float* W_O   = (const float*)d_in[11];
    float* out = (float*)d_out;

    const size_t MB = 1u << 20;
    char* w8 = (char*)d_ws;
    u16*  WOb   = (u16*)(w8 + 0);          //  2MB [1024][1024] (live to the end)
    u16*  FqkTh = (u16*)(w8 + 2  * MB);    //  4MB [2048][1024]
    u16*  FqkTl = (u16*)(w8 + 6  * MB);
    u16*  FvT   = (u16*)(w8 + 10 * MB);
    u16*  RqkTh = (u16*)(w8 + 14 * MB);    //  4MB [1024][2048]
    u16*  RqkTl = (u16*)(w8 + 18 * MB);
    u16*  RvT   = (u16*)(w8 + 22 * MB);
    float* h_q  = (float*)(w8 + 26 * MB);  //  1MB each
    float* h_k  = (float*)(w8 + 27 * MB);
    float* h_v  = (float*)(w8 + 28 * MB);
    u16*  x_hi  = (u16*)(w8 + 30 * MB);    //  8MB
    u16*  x_lo  = (u16*)(w8 + 38 * MB);
    float* P    = (float*)(w8 + 48 * MB);  // 32MB fp32 (dead after mix)
    u16*  Qh    = (u16*)(w8 + 48 * MB);    //  8MB each, [bh][s][dh] (over P)
    u16*  Ql    = (u16*)(w8 + 56 * MB);
    u16*  Kh    = (u16*)(w8 + 64 * MB);
    u16*  Kl    = (u16*)(w8 + 72 * MB);
    u16*  Vt    = (u16*)(w8 + 80 * MB);    //  8MB [bh][dh][s]
    u16*  Am    = (u16*)(w8 + 88 * MB);    //  8MB bf16 attn out
    u16*  Opart = (u16*)(w8 + 2  * MB);    // 37.75MB over FqkT*/RqkT* (dead by flash)
    float* mlws = (float*)(w8 + 40 * MB);  // 2.36MB

    dim3 blk(256);

    // casts / transposes
    cast_split<1><<<dim3(4096), blk, 0, stream>>>(x, x_hi, x_lo, 1024 * 1024);
    cast_split<0><<<dim3(1024), blk, 0, stream>>>(W_O, WOb, nullptr, 256 * 1024);
    transpose_cast<1><<<dim3(2, 32, 32), blk, 0, stream>>>(f_qk, FqkTh, FqkTl, 1024, 64, 1024);
    transpose_cast<0><<<dim3(2, 32, 32), blk, 0, stream>>>(f_v,  FvT,   nullptr, 1024, 64, 1024);
    transpose_cast<1><<<dim3(32, 64, 1), blk, 0, stream>>>(r_qk, RqkTh, RqkTl, 2048, 1024, 2048);
    transpose_cast<0><<<dim3(32, 64, 1), blk, 0, stream>>>(r_v,  RvT,   nullptr, 2048, 1024, 2048);

    // project (128x128 tiles, 1-D grid, ct-pinned XCD swizzle) + mix
    gemm_mfma<1, 2><<<dim3(512), blk, 0, stream>>>(x_hi, x_lo, FqkTh, FqkTl, P,
                                                   4096, 2048, 1024);
    mix_kernel<<<dim3(1024), blk, 0, stream>>>(P, wfqkQ, wfqkK, h_q, h_k, 1);
    gemm_mfma<0, 2><<<dim3(512), blk, 0, stream>>>(x_hi, nullptr, FvT, nullptr, P,
                                                   4096, 2048, 1024);
    mix_kernel<<<dim3(1024), blk, 0, stream>>>(P, wfv, nullptr, h_v, nullptr, 0);

    // fused restore (128x128, grid 768, ct-pinned) -> bf16 attn operands
    restore_mega<<<dim3(768), blk, 0, stream>>>(h_q, wrqkQ, h_k, wrqkK, h_v, wrv,
                                                RqkTh, RqkTl, RvT,
                                                Qh, Ql, Kh, Kl, Vt);

    // K-split flash attention: partials + combine
    flash_part<<<dim3(256, 32), blk, 0, stream>>>(Qh, Ql, Kh, Kl, Vt, Opart, mlws);
    flash_combine<<<dim3(32, 32), blk, 0, stream>>>(Opart, mlws, Am);

    // output projection (grid 256, ct-pinned)
    gemm_mfma<0, 1><<<dim3(256), blk, 0, stream>>>(Am, nullptr, WOb, nullptr, out,
                                                   4096, 1024, 1024);
}

// Round 8
// 473.420 us; speedup vs baseline: 1.8265x; 1.2964x over previous
//
#include <hip/hip_runtime.h>
#include <hip/hip_bf16.h>
#include <cstdint>
#include <cstddef>

// B=2, S=2048, D=1024, R=64, H=16, DH=64, N=32; BS=4096
typedef unsigned short u16;
typedef short bfrag __attribute__((ext_vector_type(8)));      // 8 bf16
typedef _Float16 hfrag __attribute__((ext_vector_type(8)));   // 8 fp16
typedef float f32x4 __attribute__((ext_vector_type(4)));
typedef u16 u16x8 __attribute__((ext_vector_type(8)));

__device__ __forceinline__ u16 f2bf(float v) {
    union { float f; unsigned u; } a; a.f = v;
    unsigned r = a.u + 0x7fff + ((a.u >> 16) & 1);   // RNE
    return (u16)(r >> 16);
}
__device__ __forceinline__ float bf2f(u16 u) {
    union { unsigned u; float f; } a; a.u = ((unsigned)u) << 16;
    return a.f;
}
__device__ __forceinline__ u16 f2h(float v) {
    union { _Float16 h; u16 u; } a; a.h = (_Float16)v;
    return a.u;
}
__device__ __forceinline__ f32x4 mfma_bf16(bfrag a, bfrag b, f32x4 c) {
    return __builtin_amdgcn_mfma_f32_16x16x32_bf16(a, b, c, 0, 0, 0);
}
__device__ __forceinline__ f32x4 mfma_f16(hfrag a, hfrag b, f32x4 c) {
    return __builtin_amdgcn_mfma_f32_16x16x32_f16(a, b, c, 0, 0, 0);
}
__device__ __forceinline__ void async_copy16(const void* g, void* l) {
    __builtin_amdgcn_global_load_lds(
        (const __attribute__((address_space(1))) unsigned*)g,
        (__attribute__((address_space(3))) unsigned*)l, 16, 0, 0);
}
__device__ __forceinline__ int get_xcd() {
    unsigned x;
    asm volatile("s_getreg_b32 %0, hwreg(HW_REG_XCC_ID)" : "=s"(x));
    return (int)(x & 7);
}

// ---------------------------------------------------------------------------
// elementwise cast fp32 -> bf16 hi (+lo if SPLIT); n4 = count/4
// ---------------------------------------------------------------------------
template<int SPLIT>
__global__ __launch_bounds__(256) void cast_split(const float* __restrict__ s,
                                                  u16* __restrict__ dh,
                                                  u16* __restrict__ dl, int n4)
{
    int i = blockIdx.x * 256 + threadIdx.x;
    if (i >= n4) return;
    float4 v = ((const float4*)s)[i];
    float vv[4] = {v.x, v.y, v.z, v.w};
    ushort4 h, l;
    u16* hp = (u16*)&h; u16* lp = (u16*)&l;
#pragma unroll
    for (int e = 0; e < 4; ++e) {
        u16 hb = f2bf(vv[e]);
        hp[e] = hb;
        if (SPLIT) lp[e] = f2bf(vv[e] - bf2f(hb));
    }
    ((ushort4*)dh)[i] = h;
    if (SPLIT) ((ushort4*)dl)[i] = l;
}

// ---------------------------------------------------------------------------
// transpose + cast: dst[z*C + c][r] = src[z*R*C + r*C + c]; dst pitch dpitch.
// MODE 0: bf16 single; MODE 1: bf16 hi/lo split; MODE 2: fp16 single.
// ---------------------------------------------------------------------------
template<int MODE>
__global__ __launch_bounds__(256) void transpose_cast(const float* __restrict__ src,
                                                      u16* __restrict__ dh,
                                                      u16* __restrict__ dl,
                                                      int R, int C, int dpitch)
{
    __shared__ float t[32][33];
    int z = blockIdx.z;
    const float* s = src + (size_t)z * R * C;
    int r0 = blockIdx.y * 32, c0 = blockIdx.x * 32;
    int tx = threadIdx.x & 31, ty = threadIdx.x >> 5;
#pragma unroll
    for (int p = 0; p < 4; ++p)
        t[ty + p * 8][tx] = s[(size_t)(r0 + ty + p * 8) * C + c0 + tx];
    __syncthreads();
#pragma unroll
    for (int p = 0; p < 4; ++p) {
        int rr = ty + p * 8;
        float v = t[tx][rr];
        size_t di = (size_t)(z * C + c0 + rr) * dpitch + r0 + tx;
        if (MODE == 2) {
            dh[di] = f2h(v);
        } else {
            u16 hb = f2bf(v);
            dh[di] = hb;
            if (MODE == 1) dl[di] = f2bf(v - bf2f(hb));
        }
    }
}

// ---------------------------------------------------------------------------
// MFMA bf16 GEMM 128x128, BK=32 (project / outproj), 1-D grid:
//   ct = (bid&7) + 8*(idx % CTH), rowt = idx / CTH.
// SPLIT: 3-MFMA hi/lo (~fp32). A,B pre-cast bf16 via global_load_lds.
// ---------------------------------------------------------------------------
template<int SPLIT, int CTH>
__global__ __launch_bounds__(256) void gemm_mfma(const u16* __restrict__ Agh,
                                                 const u16* __restrict__ Agl,
                                                 const u16* __restrict__ Bgh,
                                                 const u16* __restrict__ Bgl,
                                                 float* __restrict__ C,
                                                 int M, int N, int K)
{
    constexpr int NBUF = SPLIT ? 4 : 2;
    __shared__ u16 lds[NBUF * 4096];
    u16* Ath = lds;
    u16* Atl = SPLIT ? (lds + 4096) : lds;
    u16* Bth = lds + (SPLIT ? 8192 : 4096);
    u16* Btl = SPLIT ? (lds + 12288) : lds;

    const int bid = blockIdx.x;
    const int idx = bid >> 3;
    const int ct  = (bid & 7) + 8 * (idx % CTH);
    const int rowt = idx / CTH;
    const int row0 = rowt * 128;
    const int col0 = ct * 128;

    const int tid  = threadIdx.x;
    const int lane = tid & 63;
    const int wv   = tid >> 6;
    const int q    = lane >> 4;
    const int tn   = lane & 15;
    const int wm   = (wv >> 1) * 64;
    const int wn   = (wv & 1) * 64;
    const int wbase = (tid & 192) * 8;

    f32x4 acc[4][4];
#pragma unroll
    for (int i = 0; i < 4; ++i)
#pragma unroll
        for (int j = 0; j < 4; ++j) acc[i][j] = 0.f;

    for (int k0 = 0; k0 < K; k0 += 32) {
#pragma unroll
        for (int shot = 0; shot < 2; ++shot) {
            int G = tid + shot * 256;
            int row = G >> 2, kgs = G & 3;
            int kgg = kgs ^ ((row >> 1) & 3);
            size_t goffB = (size_t)(col0 + row) * K + k0 + kgg * 8;
            async_copy16(Bgh + goffB, Bth + shot * 2048 + wbase);
            if (SPLIT) async_copy16(Bgl + goffB, Btl + shot * 2048 + wbase);
            size_t goffA = (size_t)(row0 + row) * K + k0 + kgg * 8;
            async_copy16(Agh + goffA, Ath + shot * 2048 + wbase);
            if (SPLIT) async_copy16(Agl + goffA, Atl + shot * 2048 + wbase);
        }
        __syncthreads();

        bfrag ah[4], bh[4], al[4], bl[4];
#pragma unroll
        for (int i = 0; i < 4; ++i) {
            int m = wm + i * 16 + tn;
            int g = m * 4 + (q ^ ((m >> 1) & 3));
            ah[i] = *(const bfrag*)(Ath + g * 8);
            if (SPLIT) al[i] = *(const bfrag*)(Atl + g * 8);
        }
#pragma unroll
        for (int j = 0; j < 4; ++j) {
            int n = wn + j * 16 + tn;
            int g = n * 4 + (q ^ ((n >> 1) & 3));
            bh[j] = *(const bfrag*)(Bth + g * 8);
            if (SPLIT) bl[j] = *(const bfrag*)(Btl + g * 8);
        }
#pragma unroll
        for (int i = 0; i < 4; ++i)
#pragma unroll
            for (int j = 0; j < 4; ++j) {
                acc[i][j] = mfma_bf16(ah[i], bh[j], acc[i][j]);
                if (SPLIT) {
                    acc[i][j] = mfma_bf16(ah[i], bl[j], acc[i][j]);
                    acc[i][j] = mfma_bf16(al[i], bh[j], acc[i][j]);
                }
            }
        __syncthreads();
    }

#pragma unroll
    for (int i = 0; i < 4; ++i)
#pragma unroll
        for (int j = 0; j < 4; ++j)
#pragma unroll
            for (int rg = 0; rg < 4; ++rg) {
                int row = row0 + wm + i * 16 + q * 4 + rg;
                int col = col0 + wn + j * 16 + tn;
                C[(size_t)row * N + col] = acc[i][j][rg];
            }
}

// ---------------------------------------------------------------------------
// Fused restore GEMMs, fp16 single, 128x128 tiles, XCD work-queue:
// block reads HW_REG_XCC_ID, pulls a job with ct == its own XCD (steals from
// neighbors if exhausted) -> R col-slice (1 MB) guaranteed L2-resident.
// Jobs: ct in [0,8) x (sel in {Q,K,V} x rowt in [0,32)) = 8 x 96.
// A[i][k] = h[i][k&63]*w[i][k>>6] cast fp16 on the fly; B = R fp16.
// Epilogue: Q,K fp16 [bh][s][dh]; V fp16 transposed [bh][dh][s].
// ---------------------------------------------------------------------------
__global__ __launch_bounds__(256) void restore_mega(
    const float* __restrict__ h_q, const float* __restrict__ wQ,
    const float* __restrict__ h_k, const float* __restrict__ wK,
    const float* __restrict__ h_v, const float* __restrict__ wV,
    const u16* __restrict__ Rqk, const u16* __restrict__ Rv,
    u16* __restrict__ Qf, u16* __restrict__ Kf, u16* __restrict__ Vt,
    int* __restrict__ queue)
{
    __shared__ int sjob;
    const int tid = threadIdx.x;
    if (tid == 0) {
        int xcd = get_xcd();
        int job = -1;
        for (int t = 0; t < 8; ++t) {
            int qi = (xcd + t) & 7;
            int j = atomicAdd(&queue[qi], 1);
            if (j < 96) { job = qi * 96 + j; break; }
        }
        sjob = job;
    }
    __syncthreads();
    const int job = sjob;
    if (job < 0) return;
    const int ct   = job / 96;
    const int jj   = job % 96;
    const int sel  = jj >> 5;                 // 0=Q,1=K,2=V
    const int rowt = jj & 31;
    const float* hA = (sel == 0) ? h_q : (sel == 1) ? h_k : h_v;
    const float* wA = (sel == 0) ? wQ  : (sel == 1) ? wK  : wV;
    const u16* Bg = (sel < 2) ? Rqk : Rv;
    const int K = 2048;
    const int row0 = rowt * 128, col0 = ct * 128;

    __shared__ u16 lds[8192];
    u16* Ath = lds;            // 128x32 fp16
    u16* Bth = lds + 4096;     // 128x32 fp16

    const int lane = tid & 63;
    const int wv   = tid >> 6;
    const int q    = lane >> 4;
    const int tn   = lane & 15;
    const int wm   = (wv >> 1) * 64;
    const int wn   = (wv & 1) * 64;
    const int wbase = (tid & 192) * 8;

    f32x4 acc[4][4];
#pragma unroll
    for (int i = 0; i < 4; ++i)
#pragma unroll
        for (int j = 0; j < 4; ++j) acc[i][j] = 0.f;

    for (int k0 = 0; k0 < K; k0 += 32) {
        // B staging (async fp16)
#pragma unroll
        for (int shot = 0; shot < 2; ++shot) {
            int G = tid + shot * 256;
            int row = G >> 2, kgs = G & 3;
            int kgg = kgs ^ ((row >> 1) & 3);
            size_t goff = (size_t)(col0 + row) * K + k0 + kgg * 8;
            async_copy16(Bg + goff, Bth + shot * 2048 + wbase);
        }
        // A on the fly: hw product -> fp16
        {
            const int r = tid >> 1;
            float wmul = wA[(size_t)(row0 + r) * 32 + (k0 >> 6)];
#pragma unroll
            for (int gi = 0; gi < 2; ++gi) {
                int gg = (tid & 1) * 2 + gi;
                const float* sp = hA + (size_t)(row0 + r) * 64 + (k0 & 63) + gg * 8;
                float4 v0 = *(const float4*)sp;
                float4 v1 = *(const float4*)(sp + 4);
                float vv[8] = {v0.x, v0.y, v0.z, v0.w, v1.x, v1.y, v1.z, v1.w};
                u16x8 hi;
#pragma unroll
                for (int e = 0; e < 8; ++e) hi[e] = f2h(vv[e] * wmul);
                int slot = r * 4 + (gg ^ ((r >> 1) & 3));
                *(u16x8*)(Ath + slot * 8) = hi;
            }
        }
        __syncthreads();

        hfrag ah[4], bhf[4];
#pragma unroll
        for (int i = 0; i < 4; ++i) {
            int m = wm + i * 16 + tn;
            int g = m * 4 + (q ^ ((m >> 1) & 3));
            ah[i] = *(const hfrag*)(Ath + g * 8);
        }
#pragma unroll
        for (int j = 0; j < 4; ++j) {
            int n = wn + j * 16 + tn;
            int g = n * 4 + (q ^ ((n >> 1) & 3));
            bhf[j] = *(const hfrag*)(Bth + g * 8);
        }
#pragma unroll
        for (int i = 0; i < 4; ++i)
#pragma unroll
            for (int j = 0; j < 4; ++j)
                acc[i][j] = mfma_f16(ah[i], bhf[j], acc[i][j]);
        __syncthreads();
    }

#pragma unroll
    for (int i = 0; i < 4; ++i)
#pragma unroll
        for (int j = 0; j < 4; ++j)
#pragma unroll
            for (int rg = 0; rg < 4; ++rg) {
                int row = row0 + wm + i * 16 + q * 4 + rg;
                int col = col0 + wn + j * 16 + tn;
                float v = acc[i][j][rg];
                if (sel < 2) {
                    size_t ix = (((size_t)(row >> 11) * 16 + (col >> 6)) << 17)
                              | ((size_t)(row & 2047) << 6) | (size_t)(col & 63);
                    ((sel == 0) ? Qf : Kf)[ix] = f2h(v);
                } else {
                    size_t ix = ((((size_t)(row >> 11) * 16 + (col >> 6)) * 64
                                 + (size_t)(col & 63)) << 11) | (size_t)(row & 2047);
                    Vt[ix] = f2h(v);
                }
            }
}

// ---------------------------------------------------------------------------
// Mix: h1[bs,r] = sum_n w1[bs,n] * P[bs, n*64+r]  (optionally h2 with w2)
// ---------------------------------------------------------------------------
__global__ __launch_bounds__(256) void mix_kernel(const float* __restrict__ P,
                                                  const float* __restrict__ w1,
                                                  const float* __restrict__ w2,
                                                  float* __restrict__ h1,
                                                  float* __restrict__ h2,
                                                  int two)
{
    int tid = blockIdx.x * 256 + threadIdx.x;
    int bs = tid >> 6;
    int r  = tid & 63;
    const float* Pp = P + (size_t)bs * 2048 + r;
    float a = 0.f, b = 0.f;
#pragma unroll
    for (int n = 0; n < 32; ++n) {
        float p = Pp[n * 64];
        a = fmaf(w1[bs * 32 + n], p, a);
        if (two) b = fmaf(w2[bs * 32 + n], p, b);
    }
    h1[tid] = a;
    if (two) h2[tid] = b;
}

// ---------------------------------------------------------------------------
// K-split MFMA flash attention, fp16. 1-D grid 8192: bh in low bits so
// same-(bid%8) blocks share K/V slices (2 MB) if round-robin holds.
// Q,K,V,P all fp16; QK = 2 MFMAs, PV = 8 MFMAs per 64-key tile.
// ---------------------------------------------------------------------------
template<int SHOTS>
__device__ __forceinline__ void stage_tile(u16* dst, const u16* src, int rowstride,
                                           int tid, int wuni)
{
#pragma unroll
    for (int shot = 0; shot < SHOTS; ++shot) {
        int sl = shot * 256 + tid;
        int m = sl >> 3, s = sl & 7, g = s ^ (m & 7);
        async_copy16(src + (size_t)m * rowstride + g * 8, dst + shot * 2048 + wuni);
    }
}

__global__ __launch_bounds__(256) void flash_part(const u16* __restrict__ Qf_g,
                                                  const u16* __restrict__ Kf_g,
                                                  const u16* __restrict__ Vt_g,
                                                  u16* __restrict__ Opart,
                                                  float* __restrict__ ml)
{
    const int bid = blockIdx.x;
    const int idx = bid >> 3;
    const int bh  = (bid & 7) + 8 * (idx & 3);
    const int rest = idx >> 2;              // 0..255
    const int qb = 31 - (rest >> 3);        // heavy first
    const int c  = rest & 7;
    const int g  = qb >> 2, rr = qb & 3;
    const int nch = g + 1;
    if (c >= nch) return;
    const int q0 = qb * 64;
    const int slot = bh * 144 + (qb + 2 * g * (g - 1) + rr * g) + c;

    const int tid = threadIdx.x;
    const int lane = tid & 63;
    const int wv = tid >> 6;
    const int q = lane >> 4;
    const int tn = lane & 15;
    const int wuni = (tid & 192) * 8;

    __shared__ u16 sQ[4096], sK[4096], sV[4096], sP[4096];   // 32 KB

    const size_t qoff = ((size_t)bh * 2048 + q0) * 64;
    stage_tile<2>(sQ, Qf_g + qoff, 64, tid, wuni);
    __syncthreads();

    hfrag qf[2];
#pragma unroll
    for (int ks = 0; ks < 2; ++ks) {
        int m = wv * 16 + tn;
        int slt = (ks * 4 + q) ^ (m & 7);
        qf[ks] = *(const hfrag*)(sQ + m * 64 + slt * 8);
    }

    float m_i[4], l_i[4];
    f32x4 acc_o[4];
#pragma unroll
    for (int ri = 0; ri < 4; ++ri) { m_i[ri] = -3.0e38f; l_i[ri] = 0.f; }
#pragma unroll
    for (int dt = 0; dt < 4; ++dt) acc_o[dt] = 0.f;

    const size_t kbase = (size_t)bh * 2048 * 64;
    const size_t vbase = (size_t)bh * 64 * 2048;
    const int kt_end = min(4 * c + 3, qb);

    for (int kt = 4 * c; kt <= kt_end; ++kt) {
        const int k0 = kt * 64;
        __syncthreads();
        stage_tile<2>(sK, Kf_g + kbase + (size_t)k0 * 64, 64, tid, wuni);
        stage_tile<2>(sV, Vt_g + vbase + k0, 2048, tid, wuni);
        __syncthreads();

        // QK^T fp16
        f32x4 accs[4];
#pragma unroll
        for (int n = 0; n < 4; ++n) accs[n] = 0.f;
#pragma unroll
        for (int n = 0; n < 4; ++n) {
            int r = n * 16 + tn;
#pragma unroll
            for (int ks = 0; ks < 2; ++ks) {
                int slt = (ks * 4 + q) ^ (r & 7);
                hfrag kf = *(const hfrag*)(sK + r * 64 + slt * 8);
                accs[n] = mfma_f16(qf[ks], kf, accs[n]);
            }
        }
        const bool diag = (kt == qb);
#pragma unroll
        for (int n = 0; n < 4; ++n)
#pragma unroll
            for (int ri = 0; ri < 4; ++ri) {
                float v = accs[n][ri] * 0.125f;
                if (diag && (n * 16 + tn > wv * 16 + q * 4 + ri)) v = -3.0e38f;
                accs[n][ri] = v;
            }
        // online softmax (rows across 16-lane quads)
        float alpha[4], mnew[4], ssum[4];
#pragma unroll
        for (int ri = 0; ri < 4; ++ri) {
            float mx = fmaxf(fmaxf(accs[0][ri], accs[1][ri]),
                             fmaxf(accs[2][ri], accs[3][ri]));
#pragma unroll
            for (int xm = 1; xm < 16; xm <<= 1)
                mx = fmaxf(mx, __shfl_xor(mx, xm, 64));
            mnew[ri] = fmaxf(m_i[ri], mx);
            alpha[ri] = __expf(m_i[ri] - mnew[ri]);
            m_i[ri] = mnew[ri];
            ssum[ri] = 0.f;
        }
#pragma unroll
        for (int n = 0; n < 4; ++n)
#pragma unroll
            for (int ri = 0; ri < 4; ++ri) {
                float p = __expf(accs[n][ri] - mnew[ri]);
                ssum[ri] += p;
                int m = wv * 16 + q * 4 + ri;
                int cc = n * 16 + tn;
                int slt = (cc >> 3) ^ (m & 7);
                sP[m * 64 + slt * 8 + (cc & 7)] = f2h(p);
            }
#pragma unroll
        for (int ri = 0; ri < 4; ++ri) {
            float sm = ssum[ri];
#pragma unroll
            for (int xm = 1; xm < 16; xm <<= 1)
                sm += __shfl_xor(sm, xm, 64);
            l_i[ri] = l_i[ri] * alpha[ri] + sm;
#pragma unroll
            for (int dt = 0; dt < 4; ++dt) acc_o[dt][ri] *= alpha[ri];
        }
        // PV fp16 (wave-local sP rows)
#pragma unroll
        for (int ks = 0; ks < 2; ++ks) {
            int m = wv * 16 + tn;
            int slt = (ks * 4 + q) ^ (m & 7);
            hfrag pf = *(const hfrag*)(sP + m * 64 + slt * 8);
#pragma unroll
            for (int dt = 0; dt < 4; ++dt) {
                int d = dt * 16 + tn;
                int vslt = (ks * 4 + q) ^ (d & 7);
                hfrag vf = *(const hfrag*)(sV + d * 64 + vslt * 8);
                acc_o[dt] = mfma_f16(pf, vf, acc_o[dt]);
            }
        }
    }

    // partials: un-normalized O (bf16) + m,l (fp32)
#pragma unroll
    for (int dt = 0; dt < 4; ++dt)
#pragma unroll
        for (int ri = 0; ri < 4; ++ri) {
            int row = wv * 16 + q * 4 + ri;
            Opart[(size_t)slot * 4096 + row * 64 + dt * 16 + tn] = f2bf(acc_o[dt][ri]);
        }
    if (tn == 0) {
#pragma unroll
        for (int ri = 0; ri < 4; ++ri) {
            int row = wv * 16 + q * 4 + ri;
            ml[(size_t)slot * 128 + row]      = m_i[ri];
            ml[(size_t)slot * 128 + 64 + row] = l_i[ri];
        }
    }
}

// ---------------------------------------------------------------------------
// Combine partials -> bf16 [bs][d]
// ---------------------------------------------------------------------------
__global__ __launch_bounds__(256) void flash_combine(const u16* __restrict__ Opart,
                                                     const float* __restrict__ ml,
                                                     u16* __restrict__ Am)
{
    const int qb = blockIdx.x, bh = blockIdx.y;
    const int g = qb >> 2, rr = qb & 3;
    const int nch = g + 1;
    const int base = bh * 144 + (qb + 2 * g * (g - 1) + rr * g);
    const int tid = threadIdx.x;
    const int row = tid >> 2;
    const int c0  = (tid & 3) * 16;

    float mstar = -3.0e38f;
    float mc[8];
#pragma unroll
    for (int c = 0; c < 8; ++c) {
        if (c < nch) {
            mc[c] = ml[(size_t)(base + c) * 128 + row];
            mstar = fmaxf(mstar, mc[c]);
        }
    }
    float lstar = 0.f, wc[8];
#pragma unroll
    for (int c = 0; c < 8; ++c) {
        if (c < nch) {
            wc[c] = __expf(mc[c] - mstar);
            lstar += ml[(size_t)(base + c) * 128 + 64 + row] * wc[c];
        }
    }
    float o[16];
#pragma unroll
    for (int j = 0; j < 16; ++j) o[j] = 0.f;
    for (int c = 0; c < nch; ++c) {
        const u16* p = Opart + (size_t)(base + c) * 4096 + row * 64 + c0;
        u16x8 v0 = *(const u16x8*)p;
        u16x8 v1 = *(const u16x8*)(p + 8);
#pragma unroll
        for (int j = 0; j < 8; ++j) {
            o[j]     = fmaf(bf2f(v0[j]), wc[c], o[j]);
            o[j + 8] = fmaf(bf2f(v1[j]), wc[c], o[j + 8]);
        }
    }
    float inv = 1.0f / lstar;
    int srow = qb * 64 + row;
    size_t obase = ((size_t)(bh >> 4) * 2048 + srow) * 1024
                 + (size_t)((bh & 15) * 64 + c0);
    u16x8 w0, w1;
#pragma unroll
    for (int j = 0; j < 8; ++j) {
        w0[j] = f2bf(o[j] * inv);
        w1[j] = f2bf(o[j + 8] * inv);
    }
    *(u16x8*)(Am + obase)     = w0;
    *(u16x8*)(Am + obase + 8) = w1;
}

// ---------------------------------------------------------------------------
extern "C" void kernel_launch(void* const* d_in, const int* in_sizes, int n_in,
                              void* d_out, int out_size, void* d_ws, size_t ws_size,
                              hipStream_t stream)
{
    const float* x     = (const float*)d_in[0];
    const float* wfqkQ = (const float*)d_in[1];
    const float* wfqkK = (const float*)d_in[2];
    const float* wfv   = (const float*)d_in[3];
    const float* wrqkQ = (const float*)d_in[4];
    const float* wrqkK = (const float*)d_in[5];
    const float* wrv   = (const float*)d_in[6];
    const float* f_qk  = (const float*)d_in[7];
    const float* f_v   = (const float*)d_in[8];
    const float* r_qk  = (const float*)d_in[9];
    const float* r_v   = (const float*)d_in[10];
    const float* W_O   = (const float*)d_in[11];
    float* out = (float*)d_out;

    const size_t MB = 1u << 20;
    char* w8 = (char*)d_ws;
    u16*  WOb   = (u16*)(w8 + 0);          //  2MB bf16 (live to end)
    u16*  FqkTh = (u16*)(w8 + 2  * MB);    //  4MB bf16 [2048][1024]
    u16*  FqkTl = (u16*)(w8 + 6  * MB);
    u16*  FvT   = (u16*)(w8 + 10 * MB);
    u16*  RqkT  = (u16*)(w8 + 14 * MB);    //  4MB fp16 [1024][2048]
    u16*  RvT   = (u16*)(w8 + 18 * MB);    //  4MB fp16
    float* h_q  = (float*)(w8 + 22 * MB);  //  1MB each
    float* h_k  = (float*)(w8 + 23 * MB);
    float* h_v  = (float*)(w8 + 24 * MB);
    u16*  x_hi  = (u16*)(w8 + 25 * MB);    //  8MB bf16
    u16*  x_lo  = (u16*)(w8 + 33 * MB);    //  8MB
    float* P    = (float*)(w8 + 48 * MB);  // 32MB fp32 (dead after mix)
    u16*  Qf    = (u16*)(w8 + 48 * MB);    //  8MB fp16 [bh][s][dh] (over P)
    u16*  Kf    = (u16*)(w8 + 56 * MB);
    u16*  Vt    = (u16*)(w8 + 64 * MB);    //  8MB fp16 [bh][dh][s]
    u16*  Am    = (u16*)(w8 + 72 * MB);    //  8MB bf16 attn out
    u16*  Opart = (u16*)(w8 + 2  * MB);    // 37.75MB over F/R/h/x (dead by flash)
    float* mlws = (float*)(w8 + 84 * MB);  // 2.36MB
    int*  queue = (int*)(w8 + 90 * MB);    // 8 ints

    dim3 blk(256);

    // casts / transposes
    cast_split<1><<<dim3(4096), blk, 0, stream>>>(x, x_hi, x_lo, 1024 * 1024);
    cast_split<0><<<dim3(1024), blk, 0, stream>>>(W_O, WOb, nullptr, 256 * 1024);
    transpose_cast<1><<<dim3(2, 32, 32), blk, 0, stream>>>(f_qk, FqkTh, FqkTl, 1024, 64, 1024);
    transpose_cast<0><<<dim3(2, 32, 32), blk, 0, stream>>>(f_v,  FvT,   nullptr, 1024, 64, 1024);
    transpose_cast<2><<<dim3(32, 64, 1), blk, 0, stream>>>(r_qk, RqkT, nullptr, 2048, 1024, 2048);
    transpose_cast<2><<<dim3(32, 64, 1), blk, 0, stream>>>(r_v,  RvT,  nullptr, 2048, 1024, 2048);

    // project (bf16, split for f_qk) + mix
    gemm_mfma<1, 2><<<dim3(512), blk, 0, stream>>>(x_hi, x_lo, FqkTh, FqkTl, P,
                                                   4096, 2048, 1024);
    mix_kernel<<<dim3(1024), blk, 0, stream>>>(P, wfqkQ, wfqkK, h_q, h_k, 1);
    gemm_mfma<0, 2><<<dim3(512), blk, 0, stream>>>(x_hi, nullptr, FvT, nullptr, P,
                                                   4096, 2048, 1024);
    mix_kernel<<<dim3(1024), blk, 0, stream>>>(P, wfv, nullptr, h_v, nullptr, 0);

    // fused restore (fp16, XCD work-queue) -> fp16 attn operands
    hipMemsetAsync(queue, 0, 8 * sizeof(int), stream);
    restore_mega<<<dim3(768), blk, 0, stream>>>(h_q, wrqkQ, h_k, wrqkK, h_v, wrv,
                                                RqkT, RvT, Qf, Kf, Vt, queue);

    // K-split flash attention (fp16): partials + combine
    flash_part<<<dim3(8192), blk, 0, stream>>>(Qf, Kf, Vt, Opart, mlws);
    flash_combine<<<dim3(32, 32), blk, 0, stream>>>(Opart, mlws, Am);

    // output projection (bf16)
    gemm_mfma<0, 1><<<dim3(256), blk, 0, stream>>>(Am, nullptr, WOb, nullptr, out,
                                                   4096, 1024, 1024);
}